// Round 4
// baseline (618.091 us; speedup 1.0000x reference)
//
#include <hip/hip_runtime.h>
#include <cstdint>

#define N_NODES 100000
#define N_EDGES 3200000
#define F_IN 128
#define DIM 10
#define QPAD 12          // padded q/h rows: 12 floats = 48B = aligned vec loads
#define B_GRAPHS 1000
#define NBLK_N 391       // ceil(N/256)
#define RNG 128          // dst nodes per bucket
#define NBKT 782         // ceil(100000/128)
#define CAP 4608         // slots/bucket: mean 4096 + 8 sigma (binomial sigma=64)
#define CHUNK 8192       // edges per k_bucket block
#define NBLK_E 391       // ceil(E/CHUNK)
#define ACCS 11          // LDS acc row stride; gcd(11,32)=1 spreads banks

// p1 = x @ W1[:128,:] (stride 10), q1p = x @ W1[128:,:] (stride 12, padded)
__global__ __launch_bounds__(256) void k_gemm1(
    const float* __restrict__ x, const float* __restrict__ W,
    float* __restrict__ p1, float* __restrict__ q1p)
{
  int i = blockIdx.x * 256 + threadIdx.x;
  if (i >= N_NODES) return;
  const float4* __restrict__ xr = (const float4*)(x + (size_t)i * F_IN);
  float ap[DIM], aq[DIM];
  #pragma unroll
  for (int j = 0; j < DIM; ++j) { ap[j] = 0.f; aq[j] = 0.f; }
  #pragma unroll 4
  for (int k4 = 0; k4 < F_IN / 4; ++k4) {
    float4 v = xr[k4];
    const float* __restrict__ w0 = W + (k4 * 4) * DIM;
    const float* __restrict__ w1 = W + (F_IN + k4 * 4) * DIM;
    #pragma unroll
    for (int j = 0; j < DIM; ++j) {
      ap[j] += v.x * w0[j] + v.y * w0[DIM + j] + v.z * w0[2 * DIM + j] + v.w * w0[3 * DIM + j];
      aq[j] += v.x * w1[j] + v.y * w1[DIM + j] + v.z * w1[2 * DIM + j] + v.w * w1[3 * DIM + j];
    }
  }
  float* pr = p1 + (size_t)i * DIM;
  float* qr = q1p + (size_t)i * QPAD;
  #pragma unroll
  for (int j = 0; j < DIM; ++j) { pr[j] = ap[j]; qr[j] = aq[j]; }
}

// Bucket edges by dst range. One global atomic per (block,bucket); record
// writes are rank-contiguous per (block,bucket) -> L2 write-combined.
__global__ __launch_bounds__(256) void k_bucket(
    const int* __restrict__ src, const int* __restrict__ dst,
    unsigned int* __restrict__ gcur, unsigned int* __restrict__ buckets)
{
  __shared__ unsigned int hcnt[NBKT];
  __shared__ unsigned int gbase[NBKT];
  int tid = threadIdx.x;
  for (int k = tid; k < NBKT; k += 256) hcnt[k] = 0u;
  __syncthreads();
  int base = blockIdx.x * CHUNK;
  #pragma unroll
  for (int it = 0; it < CHUNK / 256; ++it) {
    int e = base + it * 256 + tid;
    if (e < N_EDGES) atomicAdd(&hcnt[(unsigned)dst[e] >> 7], 1u);
  }
  __syncthreads();
  for (int k = tid; k < NBKT; k += 256) {
    unsigned c = hcnt[k];
    gbase[k] = c ? atomicAdd(&gcur[k], c) : 0u;
    hcnt[k] = 0u;
  }
  __syncthreads();
  #pragma unroll
  for (int it = 0; it < CHUNK / 256; ++it) {
    int e = base + it * 256 + tid;
    if (e < N_EDGES) {
      unsigned d = (unsigned)dst[e];
      unsigned bkt = d >> 7;
      unsigned ofs = atomicAdd(&hcnt[bkt], 1u);
      unsigned p = gbase[bkt] + ofs;
      if (p < CAP)   // statistically impossible overflow; memory-safety only
        buckets[(size_t)bkt * CAP + p] = ((d & 127u) << 17) | (unsigned)src[e];
    }
  }
}

// Layer 1: one block per bucket. Gather q1[src] -> LDS f32 atomics, count deg,
// then fused epilogue: h = relu(p1 + mean), (p2,q2) = h @ W2.
__global__ __launch_bounds__(256) void k_lay1(
    const unsigned int* __restrict__ gcur, const unsigned int* __restrict__ buckets,
    const float* __restrict__ p1, const float* __restrict__ q1p,
    const float* __restrict__ W2,
    float* __restrict__ p2, float* __restrict__ q2p)
{
  __shared__ float acc[RNG * ACCS];
  __shared__ int cnt[RNG];
  __shared__ float w[2 * DIM * DIM];
  int tid = threadIdx.x;
  for (int k = tid; k < RNG * ACCS; k += 256) acc[k] = 0.f;
  if (tid < RNG) cnt[tid] = 0;
  for (int k = tid; k < 2 * DIM * DIM; k += 256) w[k] = W2[k];
  __syncthreads();
  int b = blockIdx.x;
  int n = min((int)gcur[b], CAP);
  const unsigned int* __restrict__ rec = buckets + (size_t)b * CAP;
  for (int r = tid; r < n; r += 256) {
    unsigned v = rec[r];
    int s = v & 0x1FFFF;
    int dl = v >> 17;
    const float4* __restrict__ q = (const float4*)(q1p + (size_t)s * QPAD);
    float4 r0 = q[0], r1 = q[1];
    float2 r2 = *(const float2*)(q1p + (size_t)s * QPAD + 8);
    float* a = acc + dl * ACCS;
    atomicAdd(&a[0], r0.x); atomicAdd(&a[1], r0.y);
    atomicAdd(&a[2], r0.z); atomicAdd(&a[3], r0.w);
    atomicAdd(&a[4], r1.x); atomicAdd(&a[5], r1.y);
    atomicAdd(&a[6], r1.z); atomicAdd(&a[7], r1.w);
    atomicAdd(&a[8], r2.x); atomicAdd(&a[9], r2.y);
    atomicAdd(&cnt[dl], 1);
  }
  __syncthreads();
  if (tid < RNG) {
    int i = b * RNG + tid;
    if (i < N_NODES) {
      float inv = 1.0f / fmaxf((float)cnt[tid], 1.0f);
      const float* __restrict__ pr = p1 + (size_t)i * DIM;
      const float* a = acc + tid * ACCS;
      float h[DIM];
      #pragma unroll
      for (int j = 0; j < DIM; ++j) h[j] = fmaxf(pr[j] + a[j] * inv, 0.0f);
      float* po = p2 + (size_t)i * DIM;
      float* qo = q2p + (size_t)i * QPAD;
      #pragma unroll
      for (int j = 0; j < DIM; ++j) {
        float aa = 0.f, bb = 0.f;
        #pragma unroll
        for (int k = 0; k < DIM; ++k) {
          aa += h[k] * w[k * DIM + j];
          bb += h[k] * w[(DIM + k) * DIM + j];
        }
        po[j] = aa; qo[j] = bb;
      }
    }
  }
}

// Layer 2: same gather on q2p; epilogue h2 = p2 + mean (stride QPAD for pool).
__global__ __launch_bounds__(256) void k_lay2(
    const unsigned int* __restrict__ gcur, const unsigned int* __restrict__ buckets,
    const float* __restrict__ p2, const float* __restrict__ q2p,
    float* __restrict__ h2)
{
  __shared__ float acc[RNG * ACCS];
  __shared__ int cnt[RNG];
  int tid = threadIdx.x;
  for (int k = tid; k < RNG * ACCS; k += 256) acc[k] = 0.f;
  if (tid < RNG) cnt[tid] = 0;
  __syncthreads();
  int b = blockIdx.x;
  int n = min((int)gcur[b], CAP);
  const unsigned int* __restrict__ rec = buckets + (size_t)b * CAP;
  for (int r = tid; r < n; r += 256) {
    unsigned v = rec[r];
    int s = v & 0x1FFFF;
    int dl = v >> 17;
    const float4* __restrict__ q = (const float4*)(q2p + (size_t)s * QPAD);
    float4 r0 = q[0], r1 = q[1];
    float2 r2 = *(const float2*)(q2p + (size_t)s * QPAD + 8);
    float* a = acc + dl * ACCS;
    atomicAdd(&a[0], r0.x); atomicAdd(&a[1], r0.y);
    atomicAdd(&a[2], r0.z); atomicAdd(&a[3], r0.w);
    atomicAdd(&a[4], r1.x); atomicAdd(&a[5], r1.y);
    atomicAdd(&a[6], r1.z); atomicAdd(&a[7], r1.w);
    atomicAdd(&a[8], r2.x); atomicAdd(&a[9], r2.y);
    atomicAdd(&cnt[dl], 1);
  }
  __syncthreads();
  if (tid < RNG) {
    int i = b * RNG + tid;
    if (i < N_NODES) {
      float inv = 1.0f / fmaxf((float)cnt[tid], 1.0f);
      const float* __restrict__ pr = p2 + (size_t)i * DIM;
      const float* a = acc + tid * ACCS;
      float* ho = h2 + (size_t)i * QPAD;
      #pragma unroll
      for (int j = 0; j < DIM; ++j) ho[j] = pr[j] + a[j] * inv;
    }
  }
}

// one wave per graph: binary-search node range in sorted batch, mean-pool,
// dot with Wfc, sigmoid -> out[b]. Zero atomics.
__global__ __launch_bounds__(64) void k_pool(
    const float* __restrict__ h2, const int* __restrict__ batch,
    const float* __restrict__ Wfc, float* __restrict__ out)
{
  int b = blockIdx.x;
  int lo = 0, hi = N_NODES;
  while (lo < hi) { int m = (lo + hi) >> 1; if (batch[m] < b) lo = m + 1; else hi = m; }
  int start = lo;
  hi = N_NODES;
  while (lo < hi) { int m = (lo + hi) >> 1; if (batch[m] < b + 1) lo = m + 1; else hi = m; }
  int end = lo;
  float sum[DIM];
  #pragma unroll
  for (int j = 0; j < DIM; ++j) sum[j] = 0.f;
  for (int r = start + (int)threadIdx.x; r < end; r += 64) {
    const float4* __restrict__ p = (const float4*)(h2 + (size_t)r * QPAD);
    float4 r0 = p[0], r1 = p[1];
    float2 r2 = *(const float2*)(h2 + (size_t)r * QPAD + 8);
    sum[0] += r0.x; sum[1] += r0.y; sum[2] += r0.z; sum[3] += r0.w;
    sum[4] += r1.x; sum[5] += r1.y; sum[6] += r1.z; sum[7] += r1.w;
    sum[8] += r2.x; sum[9] += r2.y;
  }
  #pragma unroll
  for (int m = 1; m < 64; m <<= 1) {
    #pragma unroll
    for (int j = 0; j < DIM; ++j) sum[j] += __shfl_xor(sum[j], m, 64);
  }
  if (threadIdx.x == 0) {
    float inv = 1.0f / fmaxf((float)(end - start), 1.0f);
    float acc = 0.f;
    #pragma unroll
    for (int j = 0; j < DIM; ++j) acc += sum[j] * inv * Wfc[j];
    out[b] = 1.0f / (1.0f + expf(-acc));
  }
}

extern "C" void kernel_launch(void* const* d_in, const int* in_sizes, int n_in,
                              void* d_out, int out_size, void* d_ws, size_t ws_size,
                              hipStream_t stream)
{
  const float* x     = (const float*)d_in[0];
  const int*   ei    = (const int*)d_in[1];
  const int*   batch = (const int*)d_in[2];
  const float* W1    = (const float*)d_in[3];
  const float* W2    = (const float*)d_in[4];
  const float* Wfc   = (const float*)d_in[5];
  float* out = (float*)d_out;

  const int* src = ei;            // edge_index[0]
  const int* dst = ei + N_EDGES;  // edge_index[1]

  // ---- workspace layout (4B elems; ~32 MB total) ----
  unsigned int* gcur    = (unsigned int*)d_ws;              // 782 (zeroed), pad to 1024
  unsigned int* buckets = gcur + 1024;                      // NBKT*CAP = 3,603,456
  float* q1p = (float*)(buckets + (size_t)NBKT * CAP);      // N*12
  float* q2p = q1p + (size_t)N_NODES * QPAD;                // N*12
  float* p1  = q2p + (size_t)N_NODES * QPAD;                // N*10
  float* p2  = p1 + (size_t)N_NODES * DIM;                  // N*10
  float* h2  = q1p;                                         // reuse after k_lay1

  hipMemsetAsync(gcur, 0, 1024 * sizeof(unsigned int), stream);

  k_gemm1 <<<NBLK_N, 256, 0, stream>>>(x, W1, p1, q1p);
  k_bucket<<<NBLK_E, 256, 0, stream>>>(src, dst, gcur, buckets);
  k_lay1  <<<NBKT, 256, 0, stream>>>(gcur, buckets, p1, q1p, W2, p2, q2p);
  k_lay2  <<<NBKT, 256, 0, stream>>>(gcur, buckets, p2, q2p, h2);
  k_pool  <<<B_GRAPHS, 64, 0, stream>>>(h2, batch, Wfc, out);
}